// Round 3
// baseline (297.700 us; speedup 1.0000x reference)
//
#include <hip/hip_runtime.h>

#define N_NODES 100000
#define N_EDGES 800000
#define FDIM 64
#define SCAN_BLOCK 1024
#define N_SCAN_BLOCKS ((N_NODES + SCAN_BLOCK - 1) / SCAN_BLOCK)   // 98

// ---------------------------------------------------------------------------
// Kernel 1: xw = x @ w   (fp32 vector ALU — no fp32 MFMA on CDNA4)
// One wave per row; W staged in LDS; lane f owns feature f.
// ---------------------------------------------------------------------------
__global__ __launch_bounds__(256) void gemm_xw_kernel(
    const float* __restrict__ x, const float* __restrict__ w,
    float* __restrict__ xw) {
    __shared__ float wlds[FDIM * FDIM];
    const int tid = threadIdx.x;

    const float4* w4 = reinterpret_cast<const float4*>(w);
    float4* wl4 = reinterpret_cast<float4*>(wlds);
    #pragma unroll
    for (int i = 0; i < (FDIM * FDIM / 4) / 256; ++i)
        wl4[i * 256 + tid] = w4[i * 256 + tid];
    __syncthreads();

    const int lane = tid & 63;
    const int gwave = blockIdx.x * (blockDim.x >> 6) + (tid >> 6);
    const int nwaves = gridDim.x * (blockDim.x >> 6);

    for (int row = gwave; row < N_NODES; row += nwaves) {
        const float4* xr = reinterpret_cast<const float4*>(x + (size_t)row * FDIM);
        float acc = 0.f;
        #pragma unroll
        for (int k0 = 0; k0 < FDIM / 4; ++k0) {
            float4 xv = xr[k0];  // wave-broadcast load
            acc += xv.x * wlds[(4 * k0 + 0) * FDIM + lane];
            acc += xv.y * wlds[(4 * k0 + 1) * FDIM + lane];
            acc += xv.z * wlds[(4 * k0 + 2) * FDIM + lane];
            acc += xv.w * wlds[(4 * k0 + 3) * FDIM + lane];
        }
        xw[(size_t)row * FDIM + lane] = acc;
    }
}

// --------------------------- binned pipeline -------------------------------
__global__ __launch_bounds__(256) void zero_counts_kernel(int* __restrict__ count) {
    int i = blockIdx.x * blockDim.x + threadIdx.x;
    if (i < N_NODES) count[i] = 0;
}

__global__ __launch_bounds__(256) void hist_kernel(
    const int* __restrict__ erow, int* __restrict__ count) {
    int e = blockIdx.x * blockDim.x + threadIdx.x;
    if (e < N_EDGES) atomicAdd(&count[erow[e]], 1);
}

// Per-1024-block inclusive Hillis-Steele scan -> exclusive starts + block sums
__global__ __launch_bounds__(SCAN_BLOCK) void scan_block_kernel(
    const int* __restrict__ count, int* __restrict__ starts,
    int* __restrict__ blockSums) {
    __shared__ int tmp[SCAN_BLOCK];
    const int tid = threadIdx.x;
    const int i = blockIdx.x * SCAN_BLOCK + tid;
    const int v = (i < N_NODES) ? count[i] : 0;
    tmp[tid] = v;
    __syncthreads();
    for (int off = 1; off < SCAN_BLOCK; off <<= 1) {
        int t = (tid >= off) ? tmp[tid - off] : 0;
        __syncthreads();
        tmp[tid] += t;
        __syncthreads();
    }
    if (i < N_NODES) starts[i] = tmp[tid] - v;       // exclusive
    if (tid == SCAN_BLOCK - 1) blockSums[blockIdx.x] = tmp[tid];
}

// Single-block exclusive scan of the 98 block sums (in place)
__global__ __launch_bounds__(256) void scan_sums_kernel(int* __restrict__ blockSums) {
    __shared__ int tmp[256];
    const int tid = threadIdx.x;
    const int v = (tid < N_SCAN_BLOCKS) ? blockSums[tid] : 0;
    tmp[tid] = v;
    __syncthreads();
    for (int off = 1; off < 256; off <<= 1) {
        int t = (tid >= off) ? tmp[tid - off] : 0;
        __syncthreads();
        tmp[tid] += t;
        __syncthreads();
    }
    if (tid < N_SCAN_BLOCKS) blockSums[tid] = tmp[tid] - v;   // exclusive
}

__global__ __launch_bounds__(256) void add_offsets_kernel(
    int* __restrict__ starts, const int* __restrict__ blockSums,
    int* __restrict__ cursor) {
    int i = blockIdx.x * blockDim.x + threadIdx.x;
    if (i < N_NODES) {
        int s = starts[i] + blockSums[i >> 10];
        starts[i] = s;
        cursor[i] = s;
    }
}

__global__ __launch_bounds__(256) void fill_kernel(
    const int* __restrict__ erow, int* __restrict__ cursor,
    int* __restrict__ bucket) {
    int e = blockIdx.x * blockDim.x + threadIdx.x;
    if (e < N_EDGES) {
        int pos = atomicAdd(&cursor[erow[e]], 1);
        bucket[pos] = e;
    }
}

// One 16-lane group per row, 4 rows/wave, float4 per lane. No atomics.
// out[r] = b + sum_{e in bucket(r)} xw[ecol[e]] * ew[e]
__global__ __launch_bounds__(256) void aggregate_kernel(
    const float* __restrict__ xw, const float* __restrict__ ew,
    const int* __restrict__ ecol, const int* __restrict__ bucket,
    const int* __restrict__ starts, const int* __restrict__ count,
    const float* __restrict__ b, float* __restrict__ out) {
    const int lane = threadIdx.x & 63;
    const int g = lane >> 4;        // row slot within wave
    const int s = lane & 15;        // feature quad
    const int wave = (int)((blockIdx.x * blockDim.x + threadIdx.x) >> 6);
    const int nwaves = (int)((gridDim.x * (size_t)blockDim.x) >> 6);
    const float4 bias = reinterpret_cast<const float4*>(b)[s];

    for (int r0 = wave * 4; r0 < N_NODES; r0 += nwaves * 4) {
        const int r = r0 + g;
        if (r < N_NODES) {
            float4 acc = bias;
            const int st = starts[r];
            const int cnt = count[r];
            for (int k = 0; k < cnt; ++k) {
                const int e = bucket[st + k];     // group-uniform (broadcast)
                const int c = ecol[e];
                const float wgt = ew[e];
                const float4 v =
                    reinterpret_cast<const float4*>(xw + (size_t)c * FDIM)[s];
                acc.x += v.x * wgt;
                acc.y += v.y * wgt;
                acc.z += v.z * wgt;
                acc.w += v.w * wgt;
            }
            reinterpret_cast<float4*>(out + (size_t)r * FDIM)[s] = acc;
        }
    }
}

// --------------------------- atomic fallback -------------------------------
__global__ __launch_bounds__(256) void init_out_kernel(
    float* __restrict__ out, const float* __restrict__ b) {
    const float4* b4 = reinterpret_cast<const float4*>(b);
    float4* out4 = reinterpret_cast<float4*>(out);
    const size_t total = (size_t)N_NODES * FDIM / 4;
    size_t i = (size_t)blockIdx.x * blockDim.x + threadIdx.x;
    const size_t stride = (size_t)gridDim.x * blockDim.x;
    for (; i < total; i += stride) out4[i] = b4[i & 15];
}

__global__ __launch_bounds__(256) void scatter_kernel(
    const float* __restrict__ xw, const float* __restrict__ ew,
    const int* __restrict__ erow, const int* __restrict__ ecol,
    float* __restrict__ out) {
    const int lane = threadIdx.x & 63;
    const int g = lane >> 4;
    const int s = lane & 15;
    const int wave = (int)((blockIdx.x * blockDim.x + threadIdx.x) >> 6);
    const int nwaves = (int)((gridDim.x * (size_t)blockDim.x) >> 6);

    for (int e0 = wave * 4; e0 < N_EDGES; e0 += nwaves * 4) {
        const int e = e0 + g;
        if (e < N_EDGES) {
            const int c = ecol[e];
            const int r = erow[e];
            const float wgt = ew[e];
            const float4 v =
                reinterpret_cast<const float4*>(xw + (size_t)c * FDIM)[s];
            float* dst = out + (size_t)r * FDIM + 4 * s;
            atomicAdd(dst + 0, v.x * wgt);
            atomicAdd(dst + 1, v.y * wgt);
            atomicAdd(dst + 2, v.z * wgt);
            atomicAdd(dst + 3, v.w * wgt);
        }
    }
}

extern "C" void kernel_launch(void* const* d_in, const int* in_sizes, int n_in,
                              void* d_out, int out_size, void* d_ws, size_t ws_size,
                              hipStream_t stream) {
    const float* x  = (const float*)d_in[0];
    const float* w  = (const float*)d_in[1];
    const float* b  = (const float*)d_in[2];
    const float* ew = (const float*)d_in[3];
    const int* erow = (const int*)d_in[4];
    const int* ecol = (const int*)d_in[5];
    float* out = (float*)d_out;

    // workspace layout (all 4-byte types; xw first keeps 16B alignment)
    char* ws = (char*)d_ws;
    const size_t XW_BYTES     = (size_t)N_NODES * FDIM * 4;   // 25.6 MB
    const size_t BUCKET_BYTES = (size_t)N_EDGES * 4;          // 3.2 MB
    const size_t CNT_BYTES    = (size_t)N_NODES * 4;          // 0.4 MB
    const size_t SUMS_BYTES   = 1024;
    const size_t NEED = XW_BYTES + BUCKET_BYTES + 3 * CNT_BYTES + SUMS_BYTES;

    float* xw = (float*)ws;

    // 1) projection (common to both paths)
    gemm_xw_kernel<<<2048, 256, 0, stream>>>(x, w, xw);

    if (ws_size >= NEED) {
        int* bucket    = (int*)(ws + XW_BYTES);
        int* count     = (int*)(ws + XW_BYTES + BUCKET_BYTES);
        int* starts    = (int*)(ws + XW_BYTES + BUCKET_BYTES + CNT_BYTES);
        int* cursor    = (int*)(ws + XW_BYTES + BUCKET_BYTES + 2 * CNT_BYTES);
        int* blockSums = (int*)(ws + XW_BYTES + BUCKET_BYTES + 3 * CNT_BYTES);

        const int gN = (N_NODES + 255) / 256;   // 391
        const int gE = (N_EDGES + 255) / 256;   // 3125

        zero_counts_kernel<<<gN, 256, 0, stream>>>(count);
        hist_kernel<<<gE, 256, 0, stream>>>(erow, count);
        scan_block_kernel<<<N_SCAN_BLOCKS, SCAN_BLOCK, 0, stream>>>(count, starts, blockSums);
        scan_sums_kernel<<<1, 256, 0, stream>>>(blockSums);
        add_offsets_kernel<<<gN, 256, 0, stream>>>(starts, blockSums, cursor);
        fill_kernel<<<gE, 256, 0, stream>>>(erow, cursor, bucket);
        aggregate_kernel<<<2048, 256, 0, stream>>>(xw, ew, ecol, bucket, starts,
                                                   count, b, out);
    } else {
        // fallback: fp32-atomic scatter (needs only xw in ws)
        init_out_kernel<<<2048, 256, 0, stream>>>(out, b);
        scatter_kernel<<<2048, 256, 0, stream>>>(xw, ew, erow, ecol, out);
    }
}

// Round 4
// 260.571 us; speedup vs baseline: 1.1425x; 1.1425x over previous
//
#include <hip/hip_runtime.h>

#define N_NODES 100000
#define N_EDGES 800000
#define FDIM 64
#define SCAN_BLOCK 1024
#define N_SCAN_BLOCKS ((N_NODES + SCAN_BLOCK - 1) / SCAN_BLOCK)   // 98

// ---------------------------------------------------------------------------
// Kernel 1: xw = x @ w  (fp32 vector ALU — no fp32 MFMA on CDNA4)
// One wave per row; W staged in LDS; lane f owns feature f.
// R3 fix: 4 independent accumulator chains (was 1 chain of 64 dependent FMAs
// -> latency-bound at 22% VALUBusy). Also fused: zero the degree counts.
// ---------------------------------------------------------------------------
__global__ __launch_bounds__(256) void gemm_xw_kernel(
    const float* __restrict__ x, const float* __restrict__ w,
    float* __restrict__ xw, int* __restrict__ count) {
    const int tid = threadIdx.x;
    const int gtid = blockIdx.x * 256 + tid;
    if (gtid < N_NODES) count[gtid] = 0;   // fused zero (grid 2048*256 >= N)

    __shared__ float wlds[FDIM * FDIM];
    const float4* w4 = reinterpret_cast<const float4*>(w);
    float4* wl4 = reinterpret_cast<float4*>(wlds);
    #pragma unroll
    for (int i = 0; i < (FDIM * FDIM / 4) / 256; ++i)
        wl4[i * 256 + tid] = w4[i * 256 + tid];
    __syncthreads();

    const int lane = tid & 63;
    const int gwave = blockIdx.x * 4 + (tid >> 6);
    const int nwaves = gridDim.x * 4;

    for (int row = gwave; row < N_NODES; row += nwaves) {
        const float4* xr = reinterpret_cast<const float4*>(x + (size_t)row * FDIM);
        float a0 = 0.f, a1 = 0.f, a2 = 0.f, a3 = 0.f;
        #pragma unroll 4
        for (int k0 = 0; k0 < FDIM / 4; ++k0) {
            float4 xv = xr[k0];  // wave-uniform address
            a0 += xv.x * wlds[(4 * k0 + 0) * FDIM + lane];
            a1 += xv.y * wlds[(4 * k0 + 1) * FDIM + lane];
            a2 += xv.z * wlds[(4 * k0 + 2) * FDIM + lane];
            a3 += xv.w * wlds[(4 * k0 + 3) * FDIM + lane];
        }
        xw[(size_t)row * FDIM + lane] = (a0 + a1) + (a2 + a3);
    }
}

// ---------------------------------------------------------------------------
// Kernel 2: degree histogram. R3 fix: 4 edges/thread, 4 atomics in flight
// (was 1/thread -> MLP=1, pure atomic-latency-bound).
// ---------------------------------------------------------------------------
__global__ __launch_bounds__(256) void hist_kernel(
    const int* __restrict__ erow, int* __restrict__ count) {
    const int base = (blockIdx.x * 256 + threadIdx.x) * 4;
    if (base + 3 < N_EDGES) {
        int4 r = *reinterpret_cast<const int4*>(erow + base);
        atomicAdd(&count[r.x], 1);
        atomicAdd(&count[r.y], 1);
        atomicAdd(&count[r.z], 1);
        atomicAdd(&count[r.w], 1);
    } else {
        for (int e = base; e < N_EDGES; ++e) atomicAdd(&count[erow[e]], 1);
    }
}

// ---------------------------------------------------------------------------
// Kernel 3: per-1024-block scan -> exclusive starts + block sums
// ---------------------------------------------------------------------------
__global__ __launch_bounds__(SCAN_BLOCK) void scan_block_kernel(
    const int* __restrict__ count, int* __restrict__ starts,
    int* __restrict__ blockSums) {
    __shared__ int tmp[SCAN_BLOCK];
    const int tid = threadIdx.x;
    const int i = blockIdx.x * SCAN_BLOCK + tid;
    const int v = (i < N_NODES) ? count[i] : 0;
    tmp[tid] = v;
    __syncthreads();
    for (int off = 1; off < SCAN_BLOCK; off <<= 1) {
        int t = (tid >= off) ? tmp[tid - off] : 0;
        __syncthreads();
        tmp[tid] += t;
        __syncthreads();
    }
    if (i < N_NODES) starts[i] = tmp[tid] - v;       // block-local exclusive
    if (tid == SCAN_BLOCK - 1) blockSums[blockIdx.x] = tmp[tid];
}

// ---------------------------------------------------------------------------
// Kernel 4 (fused, was 2 kernels): every block redundantly scans the 98
// block sums in LDS, then adds the offset, writes final starts + cursor.
// Also writes the CSR sentinel starts[N_NODES] = N_EDGES.
// ---------------------------------------------------------------------------
__global__ __launch_bounds__(256) void scanadd_kernel(
    int* __restrict__ starts, const int* __restrict__ blockSums,
    int* __restrict__ cursor) {
    __shared__ int ssum[128];
    const int tid = threadIdx.x;
    if (tid < 128) ssum[tid] = (tid < N_SCAN_BLOCKS) ? blockSums[tid] : 0;
    __syncthreads();
    for (int off = 1; off < 128; off <<= 1) {
        int t = (tid < 128 && tid >= off) ? ssum[tid - off] : 0;
        __syncthreads();
        if (tid < 128) ssum[tid] += t;   // inclusive scan
        __syncthreads();
    }
    const int i = blockIdx.x * 256 + tid;
    if (i < N_NODES) {
        const int j = i >> 10;
        const int add = (j == 0) ? 0 : ssum[j - 1];   // exclusive offset
        const int s = starts[i] + add;
        starts[i] = s;
        cursor[i] = s;
    } else if (i == N_NODES) {
        starts[N_NODES] = N_EDGES;                    // CSR sentinel
    }
}

// ---------------------------------------------------------------------------
// Kernel 5: bucket fill. R3 fixes: 4 edges/thread (4 atomics in flight),
// write packed (col, weight_bits) 8B records so aggregate has one less
// dependent-load level and no random ecol/ew reads.
// ---------------------------------------------------------------------------
__global__ __launch_bounds__(256) void fill_kernel(
    const int* __restrict__ erow, const int* __restrict__ ecol,
    const float* __restrict__ ew, int* __restrict__ cursor,
    uint2* __restrict__ recs) {
    const int base = (blockIdx.x * 256 + threadIdx.x) * 4;
    if (base + 3 < N_EDGES) {
        int4 r = *reinterpret_cast<const int4*>(erow + base);
        int4 c = *reinterpret_cast<const int4*>(ecol + base);
        float4 wt = *reinterpret_cast<const float4*>(ew + base);
        int p0 = atomicAdd(&cursor[r.x], 1);
        int p1 = atomicAdd(&cursor[r.y], 1);
        int p2 = atomicAdd(&cursor[r.z], 1);
        int p3 = atomicAdd(&cursor[r.w], 1);
        recs[p0] = make_uint2((unsigned)c.x, __float_as_uint(wt.x));
        recs[p1] = make_uint2((unsigned)c.y, __float_as_uint(wt.y));
        recs[p2] = make_uint2((unsigned)c.z, __float_as_uint(wt.z));
        recs[p3] = make_uint2((unsigned)c.w, __float_as_uint(wt.w));
    } else {
        for (int e = base; e < N_EDGES; ++e) {
            int p = atomicAdd(&cursor[erow[e]], 1);
            recs[p] = make_uint2((unsigned)ecol[e], __float_as_uint(ew[e]));
        }
    }
}

// ---------------------------------------------------------------------------
// Kernel 6: aggregate. 16 lanes/row, float4/lane, CSR starts[r]/starts[r+1].
// R3 fixes: packed records (2-deep dep chain, was 3), k-loop unrolled x4
// so 4 xw gathers are in flight per group.
// ---------------------------------------------------------------------------
__global__ __launch_bounds__(256) void aggregate_kernel(
    const float* __restrict__ xw, const uint2* __restrict__ recs,
    const int* __restrict__ starts, const float* __restrict__ b,
    float* __restrict__ out) {
    const int lane = threadIdx.x & 63;
    const int g = lane >> 4;        // row slot within wave
    const int s = lane & 15;        // feature quad
    const int wave = (int)((blockIdx.x * blockDim.x + threadIdx.x) >> 6);
    const int nwaves = (int)((gridDim.x * (size_t)blockDim.x) >> 6);
    const float4 bias = reinterpret_cast<const float4*>(b)[s];
    const float4* xw4 = reinterpret_cast<const float4*>(xw);

    for (int r0 = wave * 4; r0 < N_NODES; r0 += nwaves * 4) {
        const int r = r0 + g;
        if (r < N_NODES) {
            const int st = starts[r];
            const int cnt = starts[r + 1] - st;
            float4 acc = bias;
            int k = 0;
            for (; k + 4 <= cnt; k += 4) {
                uint2 e0 = recs[st + k + 0];
                uint2 e1 = recs[st + k + 1];
                uint2 e2 = recs[st + k + 2];
                uint2 e3 = recs[st + k + 3];
                float4 v0 = xw4[(size_t)e0.x * 16 + s];
                float4 v1 = xw4[(size_t)e1.x * 16 + s];
                float4 v2 = xw4[(size_t)e2.x * 16 + s];
                float4 v3 = xw4[(size_t)e3.x * 16 + s];
                const float w0 = __uint_as_float(e0.y), w1 = __uint_as_float(e1.y);
                const float w2 = __uint_as_float(e2.y), w3 = __uint_as_float(e3.y);
                acc.x += v0.x * w0 + v1.x * w1 + v2.x * w2 + v3.x * w3;
                acc.y += v0.y * w0 + v1.y * w1 + v2.y * w2 + v3.y * w3;
                acc.z += v0.z * w0 + v1.z * w1 + v2.z * w2 + v3.z * w3;
                acc.w += v0.w * w0 + v1.w * w1 + v2.w * w2 + v3.w * w3;
            }
            for (; k < cnt; ++k) {
                uint2 e0 = recs[st + k];
                float4 v0 = xw4[(size_t)e0.x * 16 + s];
                const float w0 = __uint_as_float(e0.y);
                acc.x += v0.x * w0; acc.y += v0.y * w0;
                acc.z += v0.z * w0; acc.w += v0.w * w0;
            }
            reinterpret_cast<float4*>(out + (size_t)r * FDIM)[s] = acc;
        }
    }
}

// --------------------------- atomic fallback -------------------------------
__global__ __launch_bounds__(256) void init_out_kernel(
    float* __restrict__ out, const float* __restrict__ b) {
    const float4* b4 = reinterpret_cast<const float4*>(b);
    float4* out4 = reinterpret_cast<float4*>(out);
    const size_t total = (size_t)N_NODES * FDIM / 4;
    size_t i = (size_t)blockIdx.x * blockDim.x + threadIdx.x;
    const size_t stride = (size_t)gridDim.x * blockDim.x;
    for (; i < total; i += stride) out4[i] = b4[i & 15];
}

__global__ __launch_bounds__(256) void scatter_kernel(
    const float* __restrict__ xw, const float* __restrict__ ew,
    const int* __restrict__ erow, const int* __restrict__ ecol,
    float* __restrict__ out) {
    const int lane = threadIdx.x & 63;
    const int g = lane >> 4;
    const int s = lane & 15;
    const int wave = (int)((blockIdx.x * blockDim.x + threadIdx.x) >> 6);
    const int nwaves = (int)((gridDim.x * (size_t)blockDim.x) >> 6);
    for (int e0 = wave * 4; e0 < N_EDGES; e0 += nwaves * 4) {
        const int e = e0 + g;
        if (e < N_EDGES) {
            const int c = ecol[e];
            const int r = erow[e];
            const float wgt = ew[e];
            const float4 v =
                reinterpret_cast<const float4*>(xw + (size_t)c * FDIM)[s];
            float* dst = out + (size_t)r * FDIM + 4 * s;
            atomicAdd(dst + 0, v.x * wgt);
            atomicAdd(dst + 1, v.y * wgt);
            atomicAdd(dst + 2, v.z * wgt);
            atomicAdd(dst + 3, v.w * wgt);
        }
    }
}

extern "C" void kernel_launch(void* const* d_in, const int* in_sizes, int n_in,
                              void* d_out, int out_size, void* d_ws, size_t ws_size,
                              hipStream_t stream) {
    const float* x  = (const float*)d_in[0];
    const float* w  = (const float*)d_in[1];
    const float* b  = (const float*)d_in[2];
    const float* ew = (const float*)d_in[3];
    const int* erow = (const int*)d_in[4];
    const int* ecol = (const int*)d_in[5];
    float* out = (float*)d_out;

    char* ws = (char*)d_ws;
    const size_t XW_BYTES   = (size_t)N_NODES * FDIM * 4;      // 25.6 MB
    const size_t REC_BYTES  = (size_t)N_EDGES * 8;             // 6.4 MB
    const size_t CNT_BYTES  = (size_t)N_NODES * 4;             // 0.4 MB
    const size_t ST_BYTES   = ((size_t)(N_NODES + 1) * 4 + 15) & ~(size_t)15;
    const size_t SUMS_BYTES = 512;
    const size_t NEED = XW_BYTES + REC_BYTES + CNT_BYTES + ST_BYTES +
                        CNT_BYTES + SUMS_BYTES;                // ~33.6 MB

    float* xw = (float*)ws;

    if (ws_size >= NEED) {
        uint2* recs    = (uint2*)(ws + XW_BYTES);
        int* count     = (int*)(ws + XW_BYTES + REC_BYTES);
        int* starts    = (int*)(ws + XW_BYTES + REC_BYTES + CNT_BYTES);
        int* cursor    = (int*)(ws + XW_BYTES + REC_BYTES + CNT_BYTES + ST_BYTES);
        int* blockSums = (int*)(ws + XW_BYTES + REC_BYTES + CNT_BYTES + ST_BYTES + CNT_BYTES);

        const int gE4 = (N_EDGES / 4 + 255) / 256;   // 782
        const int gN  = (N_NODES + 255) / 256 + 1;   // 392 (covers sentinel)

        gemm_xw_kernel<<<2048, 256, 0, stream>>>(x, w, xw, count);
        hist_kernel<<<gE4, 256, 0, stream>>>(erow, count);
        scan_block_kernel<<<N_SCAN_BLOCKS, SCAN_BLOCK, 0, stream>>>(count, starts, blockSums);
        scanadd_kernel<<<gN, 256, 0, stream>>>(starts, blockSums, cursor);
        fill_kernel<<<gE4, 256, 0, stream>>>(erow, ecol, ew, cursor, recs);
        aggregate_kernel<<<2048, 256, 0, stream>>>(xw, recs, starts, b, out);
    } else {
        // fallback: fp32-atomic scatter (needs only xw in ws)
        int* dummy = (int*)(ws + XW_BYTES);  // unused
        (void)dummy;
        gemm_xw_kernel<<<2048, 256, 0, stream>>>(x, w, xw, (int*)(ws + XW_BYTES - CNT_BYTES));
        init_out_kernel<<<2048, 256, 0, stream>>>(out, b);
        scatter_kernel<<<2048, 256, 0, stream>>>(xw, ew, erow, ecol, out);
    }
}